// Round 4
// baseline (313.626 us; speedup 1.0000x reference)
//
#include <hip/hip_runtime.h>
#include <hip/hip_bf16.h>

// Problem dims
constexpr int Bn   = 8;
constexpr int Cin  = 576;
constexpr int Cc   = 192;
constexpr int Hh   = 56;
constexpr int Ww   = 56;
constexpr int HWn  = Hh * Ww;          // 3136
constexpr int CKK  = Cc * 9;           // 1728

// GEMM dims (batch folded into N)
constexpr int GM = 1792;               // 1728 padded
constexpr int GK = 576;
constexpr int GN = Bn * HWn;           // 25088
constexpr int NKSTEP = GK / 32;        // 18

using f16x8 = __attribute__((ext_vector_type(8))) _Float16;
using f32x4 = __attribute__((ext_vector_type(4))) float;

__device__ __forceinline__ void async_copy16(void* lds, const void* gptr) {
    __builtin_amdgcn_global_load_lds(
        (const __attribute__((address_space(1))) unsigned int*)gptr,
        (__attribute__((address_space(3))) unsigned int*)lds, 16, 0, 0);
}

__device__ __forceinline__ float blo(unsigned int u) { return __uint_as_float(u << 16); }
__device__ __forceinline__ float bhi(unsigned int u) { return __uint_as_float(u & 0xffff0000u); }
__device__ __forceinline__ unsigned short bf16bits(float f) {
    union { __hip_bfloat16 h; unsigned short u; } c; c.h = __float2bfloat16(f); return c.u;
}

// ---------------------------------------------------------------------------
// fc_w (1728x576 f32) -> fcw16 (1792x576 f16, pad rows zero)
// ---------------------------------------------------------------------------
__global__ __launch_bounds__(256) void cast_fcw_kernel(
    const float* __restrict__ fcw, _Float16* __restrict__ out)
{
    int idx = blockIdx.x * 256 + threadIdx.x;
    int e = idx * 4;
    if (e >= GM * GK) return;
    int row = e / GK;
    union { ushort4 u; _Float16 h[4]; } pk;
    if (row < CKK) {
        float4 v = *(const float4*)&fcw[e];
        pk.h[0] = (_Float16)v.x; pk.h[1] = (_Float16)v.y;
        pk.h[2] = (_Float16)v.z; pk.h[3] = (_Float16)v.w;
    } else {
        pk.h[0] = pk.h[1] = pk.h[2] = pk.h[3] = (_Float16)0.f;
    }
    *(ushort4*)&out[e] = pk.u;
}

// ---------------------------------------------------------------------------
// x[b][k][hw] f32 -> xt[b*HW + hw][k] f16
// ---------------------------------------------------------------------------
__global__ __launch_bounds__(256) void transpose_cast_kernel(
    const float* __restrict__ x, _Float16* __restrict__ xt)
{
    __shared__ float t[32][65];
    const int b = blockIdx.z, k0 = blockIdx.y * 32, hw0 = blockIdx.x * 64;
    const int tid = threadIdx.x;
    const int col = tid & 63, kr = tid >> 6;
#pragma unroll
    for (int p = 0; p < 8; p++) {
        int k = kr + p * 4;
        t[k][col] = x[(size_t)(b * Cin + k0 + k) * HWn + hw0 + col];
    }
    __syncthreads();
    const int row = tid >> 2, cq = (tid & 3) * 8;
    union { uint4 u; _Float16 h[8]; } pk;
#pragma unroll
    for (int j = 0; j < 8; j++) pk.h[j] = (_Float16)t[cq + j][row];
    *(uint4*)&xt[(size_t)(b * HWn + hw0 + row) * GK + k0 + cq] = pk.u;
}

// ---------------------------------------------------------------------------
// MFMA GEMM — R9: LDS-arithmetic-intensity fix. R7/R8 pipelining was null
// because the 64x64 wave-tile is LDS-READ-bound (8KB frag reads per 16 MFMA
// = 16 FLOP/B caps MfmaUtil ~33%; measured 24%). New geometry: block tile
// 256x128, wave-tile 128x64 (2x2 waves) -> 12KB reads per 32 MFMA =
// 21.8 FLOP/B and half the staged-write bytes per FLOP. Sync structure is
// the verified R8 counted-vmcnt 2-phase (6 loads/thread/tile -> vmcnt(6),
// never 0 mid-loop). Same XOR swizzle (row-periodic-8, extends to 256 rows),
// same XCD remap (7 m-tiles per n), same epilogue with CKK guard.
// ---------------------------------------------------------------------------
__global__ __launch_bounds__(256) void gemm_mfma_kernel(
    const _Float16* __restrict__ A, const _Float16* __restrict__ Bm,
    __hip_bfloat16* __restrict__ logits)
{
    const int lin = blockIdx.x;
    const int g = lin & 7, s = lin >> 3;        // s: 0..174
    const int mt = s % 7, nt = (s / 7) * 8 + g;
    if (nt >= 196) return;

    __shared__ _Float16 As[2][256 * 32];        // 16 KB per buf
    __shared__ _Float16 Bs[2][128 * 32];        // 8 KB per buf

    const int tid = threadIdx.x;
    const int n0 = nt * 128;
    const int m0 = mt * 256;
    const int lane = tid & 63;
    const int wave = tid >> 6;
    const int wm = (wave >> 1) * 128;           // 2 m-waves
    const int wn = (wave & 1) * 64;             // 2 n-waves
    const int lm = lane & 15;
    const int lc = lane >> 4;                   // logical k-chunk (8 f16 = 16B)

    const int lrow = tid >> 2;
    const int koff = (((tid & 3) ^ ((tid >> 3) & 3)) << 3);  // f16 units

    int offA[8], offB[4];
#pragma unroll
    for (int i = 0; i < 8; i++) {
        int ra = wm + i * 16 + lm;
        offA[i] = ra * 32 + ((lc ^ ((ra >> 1) & 3)) << 3);
    }
#pragma unroll
    for (int j = 0; j < 4; j++) {
        int rb = wn + j * 16 + lm;
        offB[j] = rb * 32 + ((lc ^ ((rb >> 1) & 3)) << 3);
    }

    // per-thread global source pointers (advance by k each step)
    const _Float16* pA = A  + (size_t)(m0 + lrow) * GK + koff;
    const _Float16* pB = Bm + (size_t)(n0 + lrow) * GK + koff;

    // stage one K-tile into buf: A 4 panels of 64 rows, B 2 panels.
#define STAGE(buf, kk)                                                         \
    do {                                                                       \
        async_copy16(&As[buf][(size_t)tid * 8],        pA + (kk));             \
        async_copy16(&As[buf][2048  + (size_t)tid * 8], pA +  64 * GK + (kk)); \
        async_copy16(&As[buf][4096  + (size_t)tid * 8], pA + 128 * GK + (kk)); \
        async_copy16(&As[buf][6144  + (size_t)tid * 8], pA + 192 * GK + (kk)); \
        async_copy16(&Bs[buf][(size_t)tid * 8],        pB + (kk));             \
        async_copy16(&Bs[buf][2048  + (size_t)tid * 8], pB +  64 * GK + (kk)); \
    } while (0)

    // prologue: stage tiles 0 and 1 (12 outstanding loads/thread)
    STAGE(0, 0);
    STAGE(1, 32);
    asm volatile("s_waitcnt vmcnt(6)" ::: "memory");   // tile 0 landed

    f32x4 acc[8][4] = {};

    for (int t = 0; t < NKSTEP; ++t) {
        const int cur = t & 1;
        // arrival barrier: all waves' counted waits passed -> buf[cur] ready
        __builtin_amdgcn_s_barrier();
        asm volatile("" ::: "memory");

        const _Float16* Ab = &As[cur][0];
        const _Float16* Bb = &Bs[cur][0];
        f16x8 af[8], bf[4];
#pragma unroll
        for (int i = 0; i < 8; i++) af[i] = *(const f16x8*)&Ab[offA[i]];
#pragma unroll
        for (int j = 0; j < 4; j++) bf[j] = *(const f16x8*)&Bb[offB[j]];
#pragma unroll
        for (int i = 0; i < 8; i++)
#pragma unroll
            for (int j = 0; j < 4; j++)
                acc[i][j] = __builtin_amdgcn_mfma_f32_16x16x32_f16(bf[j], af[i], acc[i][j], 0, 0, 0);

        // read-done barrier: every wave consumed its ds_reads of buf[cur]
        asm volatile("" ::: "memory");
        __builtin_amdgcn_s_barrier();

        if (t + 2 < NKSTEP) {
            STAGE(cur, (t + 2) * 32);
            // wait for tile t+1 (6 of t+2's loads stay in flight)
            asm volatile("s_waitcnt vmcnt(6)" ::: "memory");
        } else {
            // tail: no new stage; ensure remaining loads (tile t+1) landed
            asm volatile("s_waitcnt vmcnt(0)" ::: "memory");
        }
    }
#undef STAGE

    const int mcol = m0 + wm + lm;
#pragma unroll
    for (int i = 0; i < 8; i++) {
        int m = mcol + i * 16;
        if (m >= CKK) continue;
#pragma unroll
        for (int j = 0; j < 4; j++) {
            int n = n0 + wn + j * 16 + lc * 4;   // 4 consecutive n, same batch
            int b = n / HWn, hw = n - b * HWn;
            uint2 pk;
            pk.x = (unsigned)bf16bits(acc[i][j][0]) | ((unsigned)bf16bits(acc[i][j][1]) << 16);
            pk.y = (unsigned)bf16bits(acc[i][j][2]) | ((unsigned)bf16bits(acc[i][j][3]) << 16);
            *(uint2*)&logits[((size_t)b * CKK + m) * HWn + hw] = pk;
        }
    }
}

// ---------------------------------------------------------------------------
// FUSED conv1 + softmax + conv2 + aggregation (R6 structure, unchanged).
// ---------------------------------------------------------------------------
__global__ __launch_bounds__(256, 4) void conv_fused_kernel(
    const float* __restrict__ x, const float* __restrict__ w1,
    const __hip_bfloat16* __restrict__ logits,
    const float* __restrict__ w2, float* __restrict__ out)
{
    const int c = blockIdx.x, hb = blockIdx.y, b = blockIdx.z;
    const int tid = threadIdx.x;
    const int h0 = hb * 14;

    __shared__ float xt[3][18][61];           // x rows h0-2..h0+15, col = w+1
    __shared__ unsigned short ft[9][16][72];  // feat rows h0-1..h0+14, col = fw+2

    // ---- stage x tile (rows h0-2..h0+15, zero-padded) ----
    for (int idx = tid; idx < 756; idx += 256) {       // 3*18*14 float4 groups
        int d = idx / 252, rem = idx - d * 252;
        int r = rem / 14, g = rem - r * 14;
        int h = h0 - 2 + r;
        float4 v = {0.f, 0.f, 0.f, 0.f};
        if (h >= 0 && h < Hh)
            v = *(const float4*)&x[((size_t)(b * Cin + 3 * c + d) * Hh + h) * Ww + 4 * g];
        xt[d][r][1 + 4 * g + 0] = v.x;
        xt[d][r][1 + 4 * g + 1] = v.y;
        xt[d][r][1 + 4 * g + 2] = v.z;
        xt[d][r][1 + 4 * g + 3] = v.w;
    }
    for (int idx = tid; idx < 108; idx += 256) {       // x edge cols 0, 57
        int d = idx / 36, rem = idx - d * 36;
        int r = rem >> 1, col = (rem & 1) ? 57 : 0;
        xt[d][r][col] = 0.f;
    }
    // ft edge zeros: cols (0,1) and (58,59), one b32 each; disjoint from
    // phase-1 writes (cols 2..57+2). 9*16*2 = 288 writes.
    for (int idx = tid; idx < 288; idx += 256) {
        int i = idx / 32, rem = idx - i * 32;
        int r = rem >> 1, side = rem & 1;
        *(unsigned int*)&ft[i][r][side ? 58 : 0] = 0u;
    }

    const bool p2 = tid < 196;
    const int row2 = tid / 14, seg2 = tid - row2 * 14;
    const int hw2 = (h0 + row2) * Ww + 4 * seg2;

    __syncthreads();

    // ---- phase 1: conv1 -> ft (16 feat rows x 14 segs of 4 px = 224) ----
    if (tid < 224) {
        const int row = tid / 14, seg = tid - (tid / 14) * 14;
        const int w0 = 4 * seg;
        const int fh = h0 - 1 + row;
        const bool valid = (fh >= 0) && (fh < Hh);

        float acc[9][4] = {};

#pragma unroll 1
        for (int d = 0; d < 3; d++) {
            // 18-float window slice for this input component
            float win[3][6];
#pragma unroll
            for (int u = 0; u < 3; u++)
#pragma unroll
                for (int k = 0; k < 6; k++)
                    win[u][k] = xt[d][row + u][w0 + k];

            const float* wb = w1 + (size_t)c * 27 + d * 9;   // uniform -> s_load
#pragma unroll
            for (int i = 0; i < 9; i++) {
                const float* wp = wb + (size_t)i * Cc * 27;
                float wgt[9];
#pragma unroll
                for (int j = 0; j < 9; j++) wgt[j] = wp[j];
#pragma unroll
                for (int u = 0; u < 3; u++)
#pragma unroll
                    for (int v = 0; v < 3; v++) {
                        float wv = wgt[u * 3 + v];
#pragma unroll
                        for (int p = 0; p < 4; p++)
                            acc[i][p] += win[u][p + v] * wv;
                    }
            }
        }

#pragma unroll
        for (int i = 0; i < 9; i++) {
            unsigned pk0 = 0u, pk1 = 0u;
            if (valid) {
                pk0 = (unsigned)bf16bits(fmaxf(acc[i][0], 0.f)) |
                      ((unsigned)bf16bits(fmaxf(acc[i][1], 0.f)) << 16);
                pk1 = (unsigned)bf16bits(fmaxf(acc[i][2], 0.f)) |
                      ((unsigned)bf16bits(fmaxf(acc[i][3], 0.f)) << 16);
            }
            unsigned int* dst = (unsigned int*)&ft[i][row][2 + w0];
            dst[0] = pk0; dst[1] = pk1;
        }
    }

    // ---- logits load, issued before the phase barrier: latency hides under
    // the barrier wait; lv live range no longer spans the phase-1 FMA loop.
    uint2 lv[9];
    if (p2) {
        const __hip_bfloat16* lbase = logits + ((size_t)b * CKK + c * 9) * HWn + hw2;
#pragma unroll
        for (int i = 0; i < 9; i++) lv[i] = *(const uint2*)&lbase[(size_t)i * HWn];
    }
    __syncthreads();

    // ---- phase 2: softmax + conv2 + aggregation (14 rows x 14 segs) ----
    if (p2) {
        const int w0 = 4 * seg2;

        float lg[9][4];
#pragma unroll
        for (int i = 0; i < 9; i++) {
            lg[i][0] = blo(lv[i].x); lg[i][1] = bhi(lv[i].x);
            lg[i][2] = blo(lv[i].y); lg[i][3] = bhi(lv[i].y);
        }
#pragma unroll
        for (int p = 0; p < 4; p++) {
            float mx = lg[0][p];
#pragma unroll
            for (int i = 1; i < 9; i++) mx = fmaxf(mx, lg[i][p]);
            float sum = 0.f;
#pragma unroll
            for (int i = 0; i < 9; i++) { lg[i][p] = __expf(lg[i][p] - mx); sum += lg[i][p]; }
            float inv = __builtin_amdgcn_rcpf(sum);
#pragma unroll
            for (int i = 0; i < 9; i++) lg[i][p] *= inv;
        }

        float oacc[4] = {};
#pragma unroll
        for (int i = 0; i < 9; i++) {
            const float* wp = w2 + ((size_t)i * Cc + c) * 9;
            float wgt[9];
#pragma unroll
            for (int j = 0; j < 9; j++) wgt[j] = wp[j];
            float cacc[4] = {};
#pragma unroll
            for (int u = 0; u < 3; u++) {
                const unsigned short* fr = &ft[i][row2 + u][w0];  // col w0 = fw w0-2
                uint2 a = *(const uint2*)fr;        // cols w0..w0+3
                uint2 b2 = *(const uint2*)(fr + 4); // cols w0+4..w0+7
                float wf[8];
                wf[0] = blo(a.x);  wf[1] = bhi(a.x);
                wf[2] = blo(a.y);  wf[3] = bhi(a.y);
                wf[4] = blo(b2.x); wf[5] = bhi(b2.x);
                wf[6] = blo(b2.y); wf[7] = bhi(b2.y);
#pragma unroll
                for (int v = 0; v < 3; v++) {
                    float wv = wgt[u * 3 + v];
#pragma unroll
                    for (int p = 0; p < 4; p++)
                        cacc[p] += wf[p + v + 1] * wv;
                }
            }
#pragma unroll
            for (int p = 0; p < 4; p++) oacc[p] += cacc[p] * lg[i][p];
        }

        float4 o;
        o.x = oacc[0]; o.y = oacc[1]; o.z = oacc[2]; o.w = oacc[3];
        *(float4*)&out[((size_t)(b * Cc + c)) * HWn + hw2] = o;
    }
}

// ---------------------------------------------------------------------------
extern "C" void kernel_launch(void* const* d_in, const int* in_sizes, int n_in,
                              void* d_out, int out_size, void* d_ws, size_t ws_size,
                              hipStream_t stream)
{
    const float* x    = (const float*)d_in[0];
    const float* fc_w = (const float*)d_in[1];
    const float* w1   = (const float*)d_in[2];
    const float* w2   = (const float*)d_in[3];
    float* out = (float*)d_out;

    // ws layout: [logits bf16 86.7MB][xt f16 28.9MB][fcw16 f16 2.1MB]
    char* ws = (char*)d_ws;
    __hip_bfloat16* logits = (__hip_bfloat16*)ws;
    _Float16* xt    = (_Float16*)(ws + (size_t)Bn * CKK * HWn * 2);
    _Float16* fcw16 = (_Float16*)(ws + (size_t)Bn * CKK * HWn * 2 + (size_t)GN * GK * 2);

    cast_fcw_kernel<<<(GM * GK / 4 + 255) / 256, 256, 0, stream>>>(fc_w, fcw16);
    transpose_cast_kernel<<<dim3(HWn / 64, GK / 32, Bn), 256, 0, stream>>>(x, xt);
    // 256x128 tiles: 7 m-tiles x 196 n-tiles, XCD remap over 8 groups
    gemm_mfma_kernel<<<8 * 25 * 7, 256, 0, stream>>>(fcw16, xt, logits);
    conv_fused_kernel<<<dim3(Cc, 4, Bn), 256, 0, stream>>>(x, w1, logits, w2, out);
}

// Round 5
// 249.245 us; speedup vs baseline: 1.2583x; 1.2583x over previous
//
#include <hip/hip_runtime.h>
#include <hip/hip_bf16.h>

// Problem dims
constexpr int Bn   = 8;
constexpr int Cin  = 576;
constexpr int Cc   = 192;
constexpr int Hh   = 56;
constexpr int Ww   = 56;
constexpr int HWn  = Hh * Ww;          // 3136
constexpr int CKK  = Cc * 9;           // 1728

// GEMM dims (batch folded into N)
constexpr int GM = 1792;               // 1728 padded
constexpr int GK = 576;
constexpr int GN = Bn * HWn;           // 25088
constexpr int NKSTEP = GK / 32;        // 18

using f16x8 = __attribute__((ext_vector_type(8))) _Float16;
using f32x4 = __attribute__((ext_vector_type(4))) float;

__device__ __forceinline__ void async_copy16(void* lds, const void* gptr) {
    __builtin_amdgcn_global_load_lds(
        (const __attribute__((address_space(1))) unsigned int*)gptr,
        (__attribute__((address_space(3))) unsigned int*)lds, 16, 0, 0);
}

__device__ __forceinline__ float blo(unsigned int u) { return __uint_as_float(u << 16); }
__device__ __forceinline__ float bhi(unsigned int u) { return __uint_as_float(u & 0xffff0000u); }
__device__ __forceinline__ unsigned short bf16bits(float f) {
    union { __hip_bfloat16 h; unsigned short u; } c; c.h = __float2bfloat16(f); return c.u;
}

// ---------------------------------------------------------------------------
// fc_w (1728x576 f32) -> fcw16 (1792x576 f16, pad rows zero)
// ---------------------------------------------------------------------------
__global__ __launch_bounds__(256) void cast_fcw_kernel(
    const float* __restrict__ fcw, _Float16* __restrict__ out)
{
    int idx = blockIdx.x * 256 + threadIdx.x;
    int e = idx * 4;
    if (e >= GM * GK) return;
    int row = e / GK;
    union { ushort4 u; _Float16 h[4]; } pk;
    if (row < CKK) {
        float4 v = *(const float4*)&fcw[e];
        pk.h[0] = (_Float16)v.x; pk.h[1] = (_Float16)v.y;
        pk.h[2] = (_Float16)v.z; pk.h[3] = (_Float16)v.w;
    } else {
        pk.h[0] = pk.h[1] = pk.h[2] = pk.h[3] = (_Float16)0.f;
    }
    *(ushort4*)&out[e] = pk.u;
}

// ---------------------------------------------------------------------------
// x[b][k][hw] f32 -> xt[b*HW + hw][k] f16
// ---------------------------------------------------------------------------
__global__ __launch_bounds__(256) void transpose_cast_kernel(
    const float* __restrict__ x, _Float16* __restrict__ xt)
{
    __shared__ float t[32][65];
    const int b = blockIdx.z, k0 = blockIdx.y * 32, hw0 = blockIdx.x * 64;
    const int tid = threadIdx.x;
    const int col = tid & 63, kr = tid >> 6;
#pragma unroll
    for (int p = 0; p < 8; p++) {
        int k = kr + p * 4;
        t[k][col] = x[(size_t)(b * Cin + k0 + k) * HWn + hw0 + col];
    }
    __syncthreads();
    const int row = tid >> 2, cq = (tid & 3) * 8;
    union { uint4 u; _Float16 h[8]; } pk;
#pragma unroll
    for (int j = 0; j < 8; j++) pk.h[j] = (_Float16)t[cq + j][row];
    *(uint4*)&xt[(size_t)(b * HWn + hw0 + row) * GK + k0 + cq] = pk.u;
}

// ---------------------------------------------------------------------------
// MFMA GEMM — R10: R9 geometry (256x128 block, 128x64 wave-tile = 21.8
// FLOP/LDS-byte) with the occupancy cliff fixed. R9's acc[8][4] went to 128
// AGPRs on top of 136 arch VGPRs = 264 > 256 -> 1 wave/SIMD -> MfmaUtil 14%.
// Fix: __launch_bounds__(256,2) caps 256 total regs/wave (2 waves/SIMD,
// 2 blocks/CU), and the MFMA loop loads ONE a-fragment then consumes it
// (live operands 20 regs, was 48) so the allocator can meet the bound
// without spilling. Sync = verified R8 counted-vmcnt 2-phase, vmcnt(6).
// ---------------------------------------------------------------------------
__global__ __launch_bounds__(256, 2) void gemm_mfma_kernel(
    const _Float16* __restrict__ A, const _Float16* __restrict__ Bm,
    __hip_bfloat16* __restrict__ logits)
{
    const int lin = blockIdx.x;
    const int g = lin & 7, s = lin >> 3;        // s: 0..174
    const int mt = s % 7, nt = (s / 7) * 8 + g;
    if (nt >= 196) return;

    __shared__ _Float16 As[2][256 * 32];        // 16 KB per buf
    __shared__ _Float16 Bs[2][128 * 32];        // 8 KB per buf

    const int tid = threadIdx.x;
    const int n0 = nt * 128;
    const int m0 = mt * 256;
    const int lane = tid & 63;
    const int wave = tid >> 6;
    const int wm = (wave >> 1) * 128;           // 2 m-waves
    const int wn = (wave & 1) * 64;             // 2 n-waves
    const int lm = lane & 15;
    const int lc = lane >> 4;                   // logical k-chunk (8 f16 = 16B)

    const int lrow = tid >> 2;
    const int koff = (((tid & 3) ^ ((tid >> 3) & 3)) << 3);  // f16 units

    int offA[8], offB[4];
#pragma unroll
    for (int i = 0; i < 8; i++) {
        int ra = wm + i * 16 + lm;
        offA[i] = ra * 32 + ((lc ^ ((ra >> 1) & 3)) << 3);
    }
#pragma unroll
    for (int j = 0; j < 4; j++) {
        int rb = wn + j * 16 + lm;
        offB[j] = rb * 32 + ((lc ^ ((rb >> 1) & 3)) << 3);
    }

    // per-thread global source pointers (advance by k each step)
    const _Float16* pA = A  + (size_t)(m0 + lrow) * GK + koff;
    const _Float16* pB = Bm + (size_t)(n0 + lrow) * GK + koff;

    // stage one K-tile into buf: A 4 panels of 64 rows, B 2 panels.
#define STAGE(buf, kk)                                                         \
    do {                                                                       \
        async_copy16(&As[buf][(size_t)tid * 8],        pA + (kk));             \
        async_copy16(&As[buf][2048  + (size_t)tid * 8], pA +  64 * GK + (kk)); \
        async_copy16(&As[buf][4096  + (size_t)tid * 8], pA + 128 * GK + (kk)); \
        async_copy16(&As[buf][6144  + (size_t)tid * 8], pA + 192 * GK + (kk)); \
        async_copy16(&Bs[buf][(size_t)tid * 8],        pB + (kk));             \
        async_copy16(&Bs[buf][2048  + (size_t)tid * 8], pB +  64 * GK + (kk)); \
    } while (0)

    // prologue: stage tiles 0 and 1 (12 outstanding loads/thread)
    STAGE(0, 0);
    STAGE(1, 32);
    asm volatile("s_waitcnt vmcnt(6)" ::: "memory");   // tile 0 landed

    f32x4 acc[8][4] = {};

    for (int t = 0; t < NKSTEP; ++t) {
        const int cur = t & 1;
        // arrival barrier: all waves' counted waits passed -> buf[cur] ready
        __builtin_amdgcn_s_barrier();
        asm volatile("" ::: "memory");

        const _Float16* Ab = &As[cur][0];
        const _Float16* Bb = &Bs[cur][0];
        f16x8 bf[4];
#pragma unroll
        for (int j = 0; j < 4; j++) bf[j] = *(const f16x8*)&Bb[offB[j]];
        // load ONE a-fragment, consume immediately: live operands = bf(16)+a(4)
#pragma unroll
        for (int i = 0; i < 8; i++) {
            f16x8 a = *(const f16x8*)&Ab[offA[i]];
#pragma unroll
            for (int j = 0; j < 4; j++)
                acc[i][j] = __builtin_amdgcn_mfma_f32_16x16x32_f16(bf[j], a, acc[i][j], 0, 0, 0);
        }

        // read-done barrier: every wave consumed its ds_reads of buf[cur]
        asm volatile("" ::: "memory");
        __builtin_amdgcn_s_barrier();

        if (t + 2 < NKSTEP) {
            STAGE(cur, (t + 2) * 32);
            // wait for tile t+1 (6 of t+2's loads stay in flight)
            asm volatile("s_waitcnt vmcnt(6)" ::: "memory");
        } else {
            // tail: no new stage; ensure remaining loads (tile t+1) landed
            asm volatile("s_waitcnt vmcnt(0)" ::: "memory");
        }
    }
#undef STAGE

    const int mcol = m0 + wm + lm;
#pragma unroll
    for (int i = 0; i < 8; i++) {
        int m = mcol + i * 16;
        if (m >= CKK) continue;
#pragma unroll
        for (int j = 0; j < 4; j++) {
            int n = n0 + wn + j * 16 + lc * 4;   // 4 consecutive n, same batch
            int b = n / HWn, hw = n - b * HWn;
            uint2 pk;
            pk.x = (unsigned)bf16bits(acc[i][j][0]) | ((unsigned)bf16bits(acc[i][j][1]) << 16);
            pk.y = (unsigned)bf16bits(acc[i][j][2]) | ((unsigned)bf16bits(acc[i][j][3]) << 16);
            *(uint2*)&logits[((size_t)b * CKK + m) * HWn + hw] = pk;
        }
    }
}

// ---------------------------------------------------------------------------
// FUSED conv1 + softmax + conv2 + aggregation (R6 structure, unchanged).
// ---------------------------------------------------------------------------
__global__ __launch_bounds__(256, 4) void conv_fused_kernel(
    const float* __restrict__ x, const float* __restrict__ w1,
    const __hip_bfloat16* __restrict__ logits,
    const float* __restrict__ w2, float* __restrict__ out)
{
    const int c = blockIdx.x, hb = blockIdx.y, b = blockIdx.z;
    const int tid = threadIdx.x;
    const int h0 = hb * 14;

    __shared__ float xt[3][18][61];           // x rows h0-2..h0+15, col = w+1
    __shared__ unsigned short ft[9][16][72];  // feat rows h0-1..h0+14, col = fw+2

    // ---- stage x tile (rows h0-2..h0+15, zero-padded) ----
    for (int idx = tid; idx < 756; idx += 256) {       // 3*18*14 float4 groups
        int d = idx / 252, rem = idx - d * 252;
        int r = rem / 14, g = rem - r * 14;
        int h = h0 - 2 + r;
        float4 v = {0.f, 0.f, 0.f, 0.f};
        if (h >= 0 && h < Hh)
            v = *(const float4*)&x[((size_t)(b * Cin + 3 * c + d) * Hh + h) * Ww + 4 * g];
        xt[d][r][1 + 4 * g + 0] = v.x;
        xt[d][r][1 + 4 * g + 1] = v.y;
        xt[d][r][1 + 4 * g + 2] = v.z;
        xt[d][r][1 + 4 * g + 3] = v.w;
    }
    for (int idx = tid; idx < 108; idx += 256) {       // x edge cols 0, 57
        int d = idx / 36, rem = idx - d * 36;
        int r = rem >> 1, col = (rem & 1) ? 57 : 0;
        xt[d][r][col] = 0.f;
    }
    // ft edge zeros: cols (0,1) and (58,59), one b32 each; disjoint from
    // phase-1 writes (cols 2..57+2). 9*16*2 = 288 writes.
    for (int idx = tid; idx < 288; idx += 256) {
        int i = idx / 32, rem = idx - i * 32;
        int r = rem >> 1, side = rem & 1;
        *(unsigned int*)&ft[i][r][side ? 58 : 0] = 0u;
    }

    const bool p2 = tid < 196;
    const int row2 = tid / 14, seg2 = tid - row2 * 14;
    const int hw2 = (h0 + row2) * Ww + 4 * seg2;

    __syncthreads();

    // ---- phase 1: conv1 -> ft (16 feat rows x 14 segs of 4 px = 224) ----
    if (tid < 224) {
        const int row = tid / 14, seg = tid - (tid / 14) * 14;
        const int w0 = 4 * seg;
        const int fh = h0 - 1 + row;
        const bool valid = (fh >= 0) && (fh < Hh);

        float acc[9][4] = {};

#pragma unroll 1
        for (int d = 0; d < 3; d++) {
            // 18-float window slice for this input component
            float win[3][6];
#pragma unroll
            for (int u = 0; u < 3; u++)
#pragma unroll
                for (int k = 0; k < 6; k++)
                    win[u][k] = xt[d][row + u][w0 + k];

            const float* wb = w1 + (size_t)c * 27 + d * 9;   // uniform -> s_load
#pragma unroll
            for (int i = 0; i < 9; i++) {
                const float* wp = wb + (size_t)i * Cc * 27;
                float wgt[9];
#pragma unroll
                for (int j = 0; j < 9; j++) wgt[j] = wp[j];
#pragma unroll
                for (int u = 0; u < 3; u++)
#pragma unroll
                    for (int v = 0; v < 3; v++) {
                        float wv = wgt[u * 3 + v];
#pragma unroll
                        for (int p = 0; p < 4; p++)
                            acc[i][p] += win[u][p + v] * wv;
                    }
            }
        }

#pragma unroll
        for (int i = 0; i < 9; i++) {
            unsigned pk0 = 0u, pk1 = 0u;
            if (valid) {
                pk0 = (unsigned)bf16bits(fmaxf(acc[i][0], 0.f)) |
                      ((unsigned)bf16bits(fmaxf(acc[i][1], 0.f)) << 16);
                pk1 = (unsigned)bf16bits(fmaxf(acc[i][2], 0.f)) |
                      ((unsigned)bf16bits(fmaxf(acc[i][3], 0.f)) << 16);
            }
            unsigned int* dst = (unsigned int*)&ft[i][row][2 + w0];
            dst[0] = pk0; dst[1] = pk1;
        }
    }

    // ---- logits load, issued before the phase barrier: latency hides under
    // the barrier wait; lv live range no longer spans the phase-1 FMA loop.
    uint2 lv[9];
    if (p2) {
        const __hip_bfloat16* lbase = logits + ((size_t)b * CKK + c * 9) * HWn + hw2;
#pragma unroll
        for (int i = 0; i < 9; i++) lv[i] = *(const uint2*)&lbase[(size_t)i * HWn];
    }
    __syncthreads();

    // ---- phase 2: softmax + conv2 + aggregation (14 rows x 14 segs) ----
    if (p2) {
        const int w0 = 4 * seg2;

        float lg[9][4];
#pragma unroll
        for (int i = 0; i < 9; i++) {
            lg[i][0] = blo(lv[i].x); lg[i][1] = bhi(lv[i].x);
            lg[i][2] = blo(lv[i].y); lg[i][3] = bhi(lv[i].y);
        }
#pragma unroll
        for (int p = 0; p < 4; p++) {
            float mx = lg[0][p];
#pragma unroll
            for (int i = 1; i < 9; i++) mx = fmaxf(mx, lg[i][p]);
            float sum = 0.f;
#pragma unroll
            for (int i = 0; i < 9; i++) { lg[i][p] = __expf(lg[i][p] - mx); sum += lg[i][p]; }
            float inv = __builtin_amdgcn_rcpf(sum);
#pragma unroll
            for (int i = 0; i < 9; i++) lg[i][p] *= inv;
        }

        float oacc[4] = {};
#pragma unroll
        for (int i = 0; i < 9; i++) {
            const float* wp = w2 + ((size_t)i * Cc + c) * 9;
            float wgt[9];
#pragma unroll
            for (int j = 0; j < 9; j++) wgt[j] = wp[j];
            float cacc[4] = {};
#pragma unroll
            for (int u = 0; u < 3; u++) {
                const unsigned short* fr = &ft[i][row2 + u][w0];  // col w0 = fw w0-2
                uint2 a = *(const uint2*)fr;        // cols w0..w0+3
                uint2 b2 = *(const uint2*)(fr + 4); // cols w0+4..w0+7
                float wf[8];
                wf[0] = blo(a.x);  wf[1] = bhi(a.x);
                wf[2] = blo(a.y);  wf[3] = bhi(a.y);
                wf[4] = blo(b2.x); wf[5] = bhi(b2.x);
                wf[6] = blo(b2.y); wf[7] = bhi(b2.y);
#pragma unroll
                for (int v = 0; v < 3; v++) {
                    float wv = wgt[u * 3 + v];
#pragma unroll
                    for (int p = 0; p < 4; p++)
                        cacc[p] += wf[p + v + 1] * wv;
                }
            }
#pragma unroll
            for (int p = 0; p < 4; p++) oacc[p] += cacc[p] * lg[i][p];
        }

        float4 o;
        o.x = oacc[0]; o.y = oacc[1]; o.z = oacc[2]; o.w = oacc[3];
        *(float4*)&out[((size_t)(b * Cc + c)) * HWn + hw2] = o;
    }
}

// ---------------------------------------------------------------------------
extern "C" void kernel_launch(void* const* d_in, const int* in_sizes, int n_in,
                              void* d_out, int out_size, void* d_ws, size_t ws_size,
                              hipStream_t stream)
{
    const float* x    = (const float*)d_in[0];
    const float* fc_w = (const float*)d_in[1];
    const float* w1   = (const float*)d_in[2];
    const float* w2   = (const float*)d_in[3];
    float* out = (float*)d_out;

    // ws layout: [logits bf16 86.7MB][xt f16 28.9MB][fcw16 f16 2.1MB]
    char* ws = (char*)d_ws;
    __hip_bfloat16* logits = (__hip_bfloat16*)ws;
    _Float16* xt    = (_Float16*)(ws + (size_t)Bn * CKK * HWn * 2);
    _Float16* fcw16 = (_Float16*)(ws + (size_t)Bn * CKK * HWn * 2 + (size_t)GN * GK * 2);

    cast_fcw_kernel<<<(GM * GK / 4 + 255) / 256, 256, 0, stream>>>(fc_w, fcw16);
    transpose_cast_kernel<<<dim3(HWn / 64, GK / 32, Bn), 256, 0, stream>>>(x, xt);
    // 256x128 tiles: 7 m-tiles x 196 n-tiles, XCD remap over 8 groups
    gemm_mfma_kernel<<<8 * 25 * 7, 256, 0, stream>>>(fcw16, xt, logits);
    conv_fused_kernel<<<dim3(Cc, 4, Bn), 256, 0, stream>>>(x, w1, logits, w2, out);
}